// Round 13
// baseline (1033.373 us; speedup 1.0000x reference)
//
#include <hip/hip_runtime.h>
#include <hip/hip_bf16.h>

// WindowAttention, round 13: barrier halving via qkvt double-buffer.
//  k_prep  : weight frags (SCALE folded) + comb table (merged launch)
//  k1_xyfrag: concat(x,y) -> bf16 A-frags in ws (revived; A read from L2)
//  k_fused : per window. Per head ONE barrier (was 2):
//      QKV GEMM (A-frags from L2, B dbuf) -> scatter q/k/vt into buf[h&1]
//      -> barrier -> swapped QK^T + in-lane softmax + pre-normalized P + PV
//      -> O -> per-wave 2KB obuf (same-wave LDS roundtrip, NO barrier)
//      -> proj wave-local rows (M=16 x N=192), pacc[12] in regs.
//    Correctness: reads(h) precede scatter(h+1) in program order; barrier(h+1)
//    orders them vs scatter(h+2) which reuses buf[h&1]. LDS 56K -> 2 blk/CU.
// R11 carried: dest-linear frag layout, no QKV sched_barrier, B-dbuf, setprio,
// cvt_pk, launch_bounds(256,2). unroll-2 / pb-prefetch (R12) reverted.

typedef __attribute__((ext_vector_type(8))) short short8;
typedef __attribute__((ext_vector_type(4))) float f32x4;

#define SCALE 0.17677669529663687f  // (192/6)^-0.5

// ---------------- ws layout ----------------
#define WQF_OFF    0ul
#define WQF_BYTES  (864ul*1024)                  // 6h*12ct*12kt frags
#define WPF_OFF    (WQF_OFF + WQF_BYTES)
#define WPF_BYTES  (144ul*1024)                  // 12ct*12kt frags
#define COMB_OFF   (WPF_OFF + WPF_BYTES)
#define COMB_BYTES (64ul*6*4096*4)
#define XYF_OFF    (COMB_OFF + COMB_BYTES)
#define XYF_BYTES  (2048ul*48*1024)              // 12kt*4mt frags per window
#define WS_NEED    (XYF_OFF + XYF_BYTES)         // ~104 MB

__device__ __forceinline__ unsigned short f2bf(float f){
  unsigned u = __builtin_bit_cast(unsigned, f);
  u = u + 0x7fffu + ((u >> 16) & 1u);            // round-to-nearest-even
  return (unsigned short)(u >> 16);
}
__device__ __forceinline__ unsigned long long pack4(float4 v){
  return (unsigned long long)f2bf(v.x) | ((unsigned long long)f2bf(v.y) << 16)
       | ((unsigned long long)f2bf(v.z) << 32) | ((unsigned long long)f2bf(v.w) << 48);
}

// HW bf16 converts (RNE, same as f2bf).
__device__ __forceinline__ unsigned short cvt1(float x){
  unsigned r;
  asm("v_cvt_pk_bf16_f32 %0, %1, %1" : "=v"(r) : "v"(x));
  return (unsigned short)r;
}
__device__ __forceinline__ uint2 pk4(float a, float b, float c, float d){
  unsigned lo, hi;
  asm("v_cvt_pk_bf16_f32 %0, %1, %2" : "=v"(lo) : "v"(a), "v"(b));
  asm("v_cvt_pk_bf16_f32 %0, %1, %2" : "=v"(hi) : "v"(c), "v"(d));
  return make_uint2(lo, hi);
}

// ---------------- merged prep: weight frags + comb table ----------------
__global__ void k_prep(const float* __restrict__ wq_f, const float* __restrict__ wp_f,
                       const float* __restrict__ mask, const float* __restrict__ btab,
                       unsigned short* __restrict__ wqf, unsigned short* __restrict__ wpf,
                       float* __restrict__ comb){
  if (blockIdx.x < 252){
    int t = blockIdx.x*256 + threadIdx.x;        // exactly 1008*64
    int fragidx = t >> 6, l = t & 63;
    const float* src; unsigned short* dst;
    float sc = 1.0f;
    if (fragidx < 864){
      int h = fragidx/144, rem = fragidx - h*144;
      int ct = rem/12, kt = rem - ct*12;
      int row = (ct>>2)*384 + h*64 + (ct&3)*16 + (l&15);
      src = wq_f + (long)row*384 + kt*32 + (l>>4)*8;
      dst = wqf + (long)fragidx*512 + l*8;
      if (ct < 4) sc = SCALE;                    // fold softmax scale into q-weights
    } else {
      int fid = fragidx - 864;
      int ct = fid/12, kt = fid - ct*12;
      int row = ct*16 + (l&15);
      src = wp_f + (long)row*384 + kt*32 + (l>>4)*8;
      dst = wpf + (long)fid*512 + l*8;
    }
    short8 v;
    #pragma unroll
    for (int e = 0; e < 8; ++e) v[e] = (short)f2bf(src[e] * sc);
    *(short8*)dst = v;
  } else {
    int idx = (blockIdx.x - 252)*256 + threadIdx.x;  // < 64*6*4096
    int j = idx & 63, i = (idx >> 6) & 63, rest = idx >> 12;
    int h = rest % 6, w = rest / 6;
    float v;
    if (i < 49 && j < 49){
      int di = i / 7 - j / 7 + 6;
      int dj = i % 7 - j % 7 + 6;
      v = btab[(di * 13 + dj) * 6 + h] + mask[(w * 49 + i) * 49 + j];
    } else {
      v = (j >= 49) ? -1e30f : 0.0f;
    }
    comb[idx] = v;
  }
}

// ---------------- k1: concat(x,y) -> A-fragments in ws ----------------
__global__ void k1_xyfrag(const float* __restrict__ x, const float* __restrict__ y,
                          unsigned short* __restrict__ xyf){
  const int kt  = blockIdx.x;                    // 0..11
  const int win = blockIdx.y;                    // 0..2047
  const int mt  = threadIdx.x >> 6;              // 0..3 (wave)
  const int l   = threadIdx.x & 63;
  const int row = mt*16 + (l & 15);
  const int c0  = kt*32 + (l >> 4)*8;
  short8 v = {};
  if (row < 49){
    const float* src = (kt < 6) ? (x + ((long)win*49 + row)*192 + c0)
                                : (y + ((long)win*49 + row)*192 + (c0 - 192));
    float4 f0 = *(const float4*)src, f1 = *(const float4*)(src+4);
    unsigned long long lo = pack4(f0), hi = pack4(f1);
    #pragma unroll
    for (int e = 0; e < 4; ++e){ v[e] = (short)(lo >> (16*e)); v[4+e] = (short)(hi >> (16*e)); }
  }
  *(short8*)(xyf + (((long)win*12 + kt)*4 + mt)*512 + l*8) = v;
}

// ---------------- fused kernel ----------------
// LDS 56 KiB: qkvt[2] double-buffer @0/@24576 (each: q 8K, k 8K, vt 8K,
// XOR-swizzled [64][64] bf16); per-wave obuf @49152 + w*2048 ([16][64] bf16).
__device__ __forceinline__ int swz(int r, int b){ return b ^ ((r & 7) << 4); }
__device__ __forceinline__ int a_q (int b, int r, int c){ return b*24576 +         swz(r, r*128 + c*2); }
__device__ __forceinline__ int a_k (int b, int r, int c){ return b*24576 + 8192  + swz(r, r*128 + c*2); }
__device__ __forceinline__ int a_vt(int b, int r, int c){ return b*24576 + 16384 + swz(r, r*128 + c*2); }
__device__ __forceinline__ int a_o (int w, int r, int c){ return 49152 + w*2048 + swz(r, r*128 + c*2); }

__global__ __launch_bounds__(256, 2)
void k_fused(const unsigned short* __restrict__ xyf,
             const unsigned short* __restrict__ wqf, const unsigned short* __restrict__ wpf,
             const float* __restrict__ bqkv, const float* __restrict__ bproj,
             const float* __restrict__ comb, float* __restrict__ out){
  __shared__ __align__(16) unsigned char smem[57344];
  const int win = blockIdx.x;
  const int tid = threadIdx.x, w = tid>>6, l = tid&63, l15 = l&15, lg = l>>4;

  // proj accumulators: wave-local rows (w*16..+16), all N=192; bias in C-init
  f32x4 pacc[12];
  #pragma unroll
  for (int nt2 = 0; nt2 < 12; ++nt2){
    float bv = bproj[nt2*16 + l15];
    #pragma unroll
    for (int j = 0; j < 4; ++j) pacc[nt2][j] = bv;
  }

  const unsigned short* Ab = xyf + (long)win*24576;   // 12kt*4mt frags (L2-resident)

  #pragma unroll 1
  for (int h = 0; h < 6; ++h){
    const int cur = h & 1;

    // comb tile prefetch (consumed post-QK^T; hides under the GEMM)
    const float* cb = comb + ((long)((win & 63)*6 + h))*4096 + (w*16 + l15)*64 + lg*4;
    float4 cbv[4];
    #pragma unroll
    for (int nt = 0; nt < 4; ++nt) cbv[nt] = *(const float4*)(cb + nt*16);

    float bias[3];
    #pragma unroll
    for (int nt = 0; nt < 3; ++nt){
      int ct = w*3 + nt, s = ct >> 2;
      bias[nt] = bqkv[s*384 + h*64 + (ct & 3)*16 + l15];
      if (s == 0) bias[nt] *= SCALE;
    }

    // ---- QKV GEMM: A-frags from L2 (global), B dbuf from L2 ----
    const unsigned short* Bb = wqf + ((long)h*12 + w*3)*12*512;
    short8 bB[2][3];
    #pragma unroll
    for (int nt = 0; nt < 3; ++nt)
      bB[0][nt] = *(const short8*)(Bb + (nt*12)*512 + l*8);
    f32x4 acc[4][3];
    #pragma unroll
    for (int mt = 0; mt < 4; ++mt)
      #pragma unroll
      for (int nt = 0; nt < 3; ++nt)
        #pragma unroll
        for (int j = 0; j < 4; ++j) acc[mt][nt][j] = bias[nt];

    #pragma unroll
    for (int kt = 0; kt < 12; ++kt){
      const int curb = kt & 1, nxtb = curb ^ 1;
      if (kt < 11){
        #pragma unroll
        for (int nt = 0; nt < 3; ++nt)
          bB[nxtb][nt] = *(const short8*)(Bb + (nt*12 + kt+1)*512 + l*8);
      }
      short8 aA[4];
      #pragma unroll
      for (int mt = 0; mt < 4; ++mt)
        aA[mt] = *(const short8*)(Ab + (kt*4 + mt)*512 + l*8);
      __builtin_amdgcn_s_setprio(1);
      #pragma unroll
      for (int nt = 0; nt < 3; ++nt){
        #pragma unroll
        for (int mt = 0; mt < 4; ++mt)
          acc[mt][nt] = __builtin_amdgcn_mfma_f32_16x16x32_bf16(aA[mt], bB[curb][nt], acc[mt][nt], 0, 0, 0);
      }
      __builtin_amdgcn_s_setprio(0);
    }

    // ---- scatter q / k (b16) and vt (transposed, b64) into buf[cur] ----
    #pragma unroll
    for (int nt = 0; nt < 3; ++nt){
      int ct = w*3 + nt, s = ct >> 2, d16 = (ct & 3) * 16;
      if (s == 2){
        #pragma unroll
        for (int mt = 0; mt < 4; ++mt){
          uint2 p = pk4(acc[mt][nt][0], acc[mt][nt][1], acc[mt][nt][2], acc[mt][nt][3]);
          *(uint2*)(smem + a_vt(cur, d16 + l15, mt*16 + lg*4)) = p;
        }
      } else {
        #pragma unroll
        for (int mt = 0; mt < 4; ++mt){
          #pragma unroll
          for (int j = 0; j < 4; ++j){
            int row = mt*16 + lg*4 + j;
            int addr = (s == 0) ? a_q(cur, row, d16 + l15) : a_k(cur, row, d16 + l15);
            *(unsigned short*)(smem + addr) = cvt1(acc[mt][nt][j]);
          }
        }
      }
    }
    __syncthreads();   // the ONLY barrier per head

    // ---- S^T = K * Q^T : lane owns q-row w*16+l15, holds 64 k-scores ----
    short8 bq[2];
    #pragma unroll
    for (int ks = 0; ks < 2; ++ks)
      bq[ks] = *(const short8*)(smem + a_q(cur, w*16 + l15, ks*32 + lg*8));
    f32x4 st[4] = {};
    __builtin_amdgcn_s_setprio(1);
    #pragma unroll
    for (int ks = 0; ks < 2; ++ks){
      #pragma unroll
      for (int nt = 0; nt < 4; ++nt){
        short8 ak = *(const short8*)(smem + a_k(cur, nt*16 + l15, ks*32 + lg*8));
        st[nt] = __builtin_amdgcn_mfma_f32_16x16x32_bf16(ak, bq[ks], st[nt], 0, 0, 0);
      }
    }
    __builtin_amdgcn_s_setprio(0);
    // + (rpb+mask); softmax over k: in-lane 16 + cross-lane ^16,^32
    #pragma unroll
    for (int nt = 0; nt < 4; ++nt){
      st[nt][0] += cbv[nt].x; st[nt][1] += cbv[nt].y;
      st[nt][2] += cbv[nt].z; st[nt][3] += cbv[nt].w;
    }
    float mx;
    {
      float m0 = fmaxf(fmaxf(st[0][0], st[0][1]), fmaxf(st[0][2], st[0][3]));
      float m1 = fmaxf(fmaxf(st[1][0], st[1][1]), fmaxf(st[1][2], st[1][3]));
      float m2 = fmaxf(fmaxf(st[2][0], st[2][1]), fmaxf(st[2][2], st[2][3]));
      float m3 = fmaxf(fmaxf(st[3][0], st[3][1]), fmaxf(st[3][2], st[3][3]));
      mx = fmaxf(fmaxf(m0, m1), fmaxf(m2, m3));
    }
    mx = fmaxf(mx, __shfl_xor(mx, 16));
    mx = fmaxf(mx, __shfl_xor(mx, 32));
    float ssum = 0.f;
    #pragma unroll
    for (int nt = 0; nt < 4; ++nt){
      #pragma unroll
      for (int j = 0; j < 4; ++j){
        float e = __expf(st[nt][j] - mx);
        st[nt][j] = e; ssum += e;
      }
    }
    ssum += __shfl_xor(ssum, 16);
    ssum += __shfl_xor(ssum, 32);
    const float inv = 1.0f / ssum;

    // pre-normalized P -> q buffer (own rows; b64 writes)
    #pragma unroll
    for (int nt = 0; nt < 4; ++nt){
      uint2 p = pk4(st[nt][0]*inv, st[nt][1]*inv, st[nt][2]*inv, st[nt][3]*inv);
      *(uint2*)(smem + a_q(cur, w*16 + l15, nt*16 + lg*4)) = p;
    }

    // ---- O = Pn * V ----
    short8 ap[2];
    #pragma unroll
    for (int ks = 0; ks < 2; ++ks)
      ap[ks] = *(const short8*)(smem + a_q(cur, w*16 + l15, ks*32 + lg*8));
    f32x4 oacc[4] = {};
    __builtin_amdgcn_s_setprio(1);
    #pragma unroll
    for (int ks = 0; ks < 2; ++ks){
      #pragma unroll
      for (int nt = 0; nt < 4; ++nt){
        short8 bv = *(const short8*)(smem + a_vt(cur, nt*16 + l15, ks*32 + lg*8));
        oacc[nt] = __builtin_amdgcn_mfma_f32_16x16x32_bf16(ap[ks], bv, oacc[nt], 0, 0, 0);
      }
    }
    __builtin_amdgcn_s_setprio(0);

    // ---- O -> per-wave obuf (C-layout writes), same-wave roundtrip, NO barrier ----
    #pragma unroll
    for (int nt = 0; nt < 4; ++nt)
      #pragma unroll
      for (int j = 0; j < 4; ++j)
        *(unsigned short*)(smem + a_o(w, lg*4 + j, nt*16 + l15)) = cvt1(oacc[nt][j]);

    // ---- proj (wave-local rows): pacc[nt2] += O_rows(w) @ wp[nt2, h-slice]^T ----
    #pragma unroll
    for (int ks = 0; ks < 2; ++ks){
      short8 aO = *(const short8*)(smem + a_o(w, l15, ks*32 + lg*8));
      __builtin_amdgcn_s_setprio(1);
      #pragma unroll
      for (int nt2 = 0; nt2 < 12; ++nt2){
        short8 bb = *(const short8*)(wpf + ((long)nt2*12 + h*2 + ks)*512 + l*8);
        pacc[nt2] = __builtin_amdgcn_mfma_f32_16x16x32_bf16(aO, bb, pacc[nt2], 0, 0, 0);
      }
      __builtin_amdgcn_s_setprio(0);
    }
  }

  // ---- epilogue: store f32 own rows < 49 (bias already in pacc) ----
  #pragma unroll
  for (int j = 0; j < 4; ++j){
    int row = w*16 + lg*4 + j;
    if (row < 49){
      float* o = out + ((long)win*49 + row)*192;
      #pragma unroll
      for (int nt2 = 0; nt2 < 12; ++nt2)
        o[nt2*16 + l15] = pacc[nt2][j];
    }
  }
}

// ================= fallback (round-2 fused kernel, if ws too small) =================
#define FB_WQ_ELEMS (1152*384)
#define FB_WP_ELEMS (192*384)
#define FB_WP_OFF   (FB_WQ_ELEMS*2)
#define FB_COMB_OFF (FB_WP_OFF + FB_WP_ELEMS*2)

__global__ void prep_weights_fb(const float* __restrict__ wq_f, const float* __restrict__ wp_f,
                                unsigned short* __restrict__ wq, unsigned short* __restrict__ wp){
  int gid = blockIdx.x * 256 + threadIdx.x;
  if (gid < FB_WQ_ELEMS) wq[gid] = f2bf(wq_f[gid]);
  else { int g = gid - FB_WQ_ELEMS; if (g < FB_WP_ELEMS) wp[g] = f2bf(wp_f[g]); }
}
__global__ void prep_comb_fb(const float* __restrict__ mask, const float* __restrict__ btab,
                             float* __restrict__ comb){
  int idx = blockIdx.x * 256 + threadIdx.x;
  int j = idx & 63, i = (idx >> 6) & 63, rest = idx >> 12;
  int h = rest % 6, w = rest / 6;
  float v;
  if (i < 49 && j < 49){
    int di = i / 7 - j / 7 + 6;
    int dj = i % 7 - j % 7 + 6;
    v = btab[(di * 13 + dj) * 6 + h] + mask[(w * 49 + i) * 49 + j];
  } else {
    v = (j >= 49) ? -1e30f : 0.0f;
  }
  comb[idx] = v;
}
__device__ __forceinline__ int fb_xy(int r, int c){ return 0      + swz(r, r*768 + c*2); }
__device__ __forceinline__ int fb_q (int r, int c){ return 49152  + swz(r, r*128 + c*2); }
__device__ __forceinline__ int fb_k (int r, int c){ return 57344  + swz(r, r*128 + c*2); }
__device__ __forceinline__ int fb_vt(int r, int c){ return 65536  + swz(r, r*128 + c*2); }
__device__ __forceinline__ int fb_p (int r, int c){ return 73728  + swz(r, r*128 + c*2); }

__global__ __launch_bounds__(256, 2)
void fused_attn_fb(const float* __restrict__ x, const float* __restrict__ y,
                   const float* __restrict__ bqkv, const float* __restrict__ bproj,
                   const unsigned short* __restrict__ wq, const unsigned short* __restrict__ wp,
                   const float* __restrict__ comb, float* __restrict__ out){
  __shared__ __align__(16) unsigned char smem[81920];
  const int b = blockIdx.x, tid = threadIdx.x;
  const int w = tid>>6, l = tid&63, l15 = l&15, lg = l>>4;
  {
    const float4* x4 = (const float4*)x + b * 2352;
    const float4* y4 = (const float4*)y + b * 2352;
    for (int idx = tid; idx < 2352; idx += 256){
      int r = idx / 48, c4 = (idx % 48) * 4;
      float4 vx = x4[idx], vy = y4[idx];
      *(unsigned long long*)(smem + fb_xy(r, c4))       = pack4(vx);
      *(unsigned long long*)(smem + fb_xy(r, 192 + c4)) = pack4(vy);
    }
    for (int idx = tid; idx < 1440; idx += 256){
      int r = 49 + idx / 96, c4 = (idx % 96) * 4;
      *(unsigned long long*)(smem + fb_xy(r, c4)) = 0ull;
    }
  }
  __syncthreads();
  const float* cbB = comb + (long)(b & 63) * (6 * 4096);
  f32x4 pacc[4][3] = {};
  int np[3]; float bp[3];
  #pragma unroll
  for (int nt = 0; nt < 3; ++nt){ np[nt] = w*48 + nt*16 + l15; bp[nt] = bproj[np[nt]]; }
  #pragma unroll 1
  for (int h = 0; h < 6; ++h){
    f32x4 acc[4][3] = {};
    int wrow[3]; float bias[3];
    #pragma unroll
    for (int nt = 0; nt < 3; ++nt){
      int n = np[nt];
      wrow[nt] = (n >> 6) * 384 + h * 64 + (n & 63);
      bias[nt] = bqkv[wrow[nt]];
    }
    #pragma unroll 4
    for (int kt = 0; kt < 12; ++kt){
      int k0 = kt * 32;
      short8 a[4];
      #pragma unroll
      for (int mt = 0; mt < 4; ++mt)
        a[mt] = *(const short8*)(smem + fb_xy(mt*16 + l15, k0 + lg*8));
      #pragma unroll
      for (int nt = 0; nt < 3; ++nt){
        short8 bb = *(const short8*)(wq + (long)wrow[nt]*384 + k0 + lg*8);
        #pragma unroll
        for (int mt = 0; mt < 4; ++mt)
          acc[mt][nt] = __builtin_amdgcn_mfma_f32_16x16x32_bf16(a[mt], bb, acc[mt][nt], 0, 0, 0);
      }
    }
    #pragma unroll
    for (int nt = 0; nt < 3; ++nt){
      int n = np[nt], s = n >> 6, d = n & 63;
      #pragma unroll
      for (int mt = 0; mt < 4; ++mt){
        #pragma unroll
        for (int j = 0; j < 4; ++j){
          int row = mt*16 + lg*4 + j;
          float v = acc[mt][nt][j] + bias[nt];
          if (s == 0) v *= SCALE;
          int addr = (s==0) ? fb_q(row,d) : (s==1) ? fb_k(row,d) : fb_vt(d,row);
          *(unsigned short*)(smem + addr) = f2bf(v);
        }
      }
    }
    __syncthreads();
    short8 aq[2];
    #pragma unroll
    for (int ks = 0; ks < 2; ++ks)
      aq[ks] = *(const short8*)(smem + fb_q(w*16 + l15, ks*32 + lg*8));
    f32x4 sacc[4] = {};
    #pragma unroll
    for (int ks = 0; ks < 2; ++ks)
      #pragma unroll
      for (int nt = 0; nt < 4; ++nt){
        short8 bk = *(const short8*)(smem + fb_k(nt*16 + l15, ks*32 + lg*8));
        sacc[nt] = __builtin_amdgcn_mfma_f32_16x16x32_bf16(aq[ks], bk, sacc[nt], 0, 0, 0);
      }
    const float* cb = cbB + h * 4096;
    float rs[4];
    #pragma unroll
    for (int j = 0; j < 4; ++j){
      int r = w*16 + lg*4 + j;
      #pragma unroll
      for (int nt = 0; nt < 4; ++nt) sacc[nt][j] += cb[r*64 + nt*16 + l15];
      float m = fmaxf(fmaxf(sacc[0][j], sacc[1][j]), fmaxf(sacc[2][j], sacc[3][j]));
      #pragma unroll
      for (int dlt = 1; dlt < 16; dlt <<= 1) m = fmaxf(m, __shfl_xor(m, dlt));
      float ssum = 0.f;
      #pragma unroll
      for (int nt = 0; nt < 4; ++nt){
        float e = __expf(sacc[nt][j] - m);
        sacc[nt][j] = e; ssum += e;
      }
      #pragma unroll
      for (int dlt = 1; dlt < 16; dlt <<= 1) ssum += __shfl_xor(ssum, dlt);
      rs[j] = ssum;
      #pragma unroll
      for (int nt = 0; nt < 4; ++nt)
        *(unsigned short*)(smem + fb_p(r, nt*16 + l15)) = f2bf(sacc[nt][j]);
    }
    short8 ap[2];
    #pragma unroll
    for (int ks = 0; ks < 2; ++ks)
      ap[ks] = *(const short8*)(smem + fb_p(w*16 + l15, ks*32 + lg*8));
    f32x4 oacc[4] = {};
    #pragma unroll
    for (int ks = 0; ks < 2; ++ks)
      #pragma unroll
      for (int nt = 0; nt < 4; ++nt){
        short8 bv = *(const short8*)(smem + fb_vt(nt*16 + l15, ks*32 + lg*8));
        oacc[nt] = __builtin_amdgcn_mfma_f32_16x16x32_bf16(ap[ks], bv, oacc[nt], 0, 0, 0);
      }
    float inv[4];
    #pragma unroll
    for (int j = 0; j < 4; ++j) inv[j] = 1.0f / rs[j];
    #pragma unroll
    for (int nt = 0; nt < 4; ++nt)
      #pragma unroll
      for (int j = 0; j < 4; ++j){
        int row = w*16 + lg*4 + j;
        *(unsigned short*)(smem + fb_p(row, nt*16 + l15)) = f2bf(oacc[nt][j] * inv[j]);
      }
    __syncthreads();
    #pragma unroll
    for (int ks = 0; ks < 2; ++ks){
      short8 ao8[4];
      #pragma unroll
      for (int mt = 0; mt < 4; ++mt)
        ao8[mt] = *(const short8*)(smem + fb_p(mt*16 + l15, ks*32 + lg*8));
      #pragma unroll
      for (int nt = 0; nt < 3; ++nt){
        short8 bb = *(const short8*)(wp + (long)np[nt]*384 + h*64 + ks*32 + lg*8);
        #pragma unroll
        for (int mt = 0; mt < 4; ++mt)
          pacc[mt][nt] = __builtin_amdgcn_mfma_f32_16x16x32_bf16(ao8[mt], bb, pacc[mt][nt], 0, 0, 0);
      }
    }
  }
  #pragma unroll
  for (int mt = 0; mt < 4; ++mt)
    #pragma unroll
    for (int j = 0; j < 4; ++j){
      int row = mt*16 + lg*4 + j;
      if (row < 49){
        float* o = out + ((long)b*49 + row)*192;
        #pragma unroll
        for (int nt = 0; nt < 3; ++nt)
          o[np[nt]] = pacc[mt][nt][j] + bp[nt];
      }
    }
}

// ---------------- launch ----------------
extern "C" void kernel_launch(void* const* d_in, const int* in_sizes, int n_in,
                              void* d_out, int out_size, void* d_ws, size_t ws_size,
                              hipStream_t stream){
  (void)in_sizes; (void)n_in; (void)out_size;
  const float* x     = (const float*)d_in[0];
  const float* y     = (const float*)d_in[1];
  const float* mask  = (const float*)d_in[2];
  const float* wq_f  = (const float*)d_in[3];
  const float* bqkv  = (const float*)d_in[4];
  const float* wp_f  = (const float*)d_in[5];
  const float* bproj = (const float*)d_in[6];
  const float* btab  = (const float*)d_in[7];
  float* out = (float*)d_out;

  if (ws_size >= WS_NEED){
    unsigned short* wqf = (unsigned short*)((char*)d_ws + WQF_OFF);
    unsigned short* wpf = (unsigned short*)((char*)d_ws + WPF_OFF);
    float*          cmb = (float*)((char*)d_ws + COMB_OFF);
    unsigned short* xyf = (unsigned short*)((char*)d_ws + XYF_OFF);
    hipLaunchKernelGGL(k_prep,    dim3(6396),    dim3(256), 0, stream,
                       wq_f, wp_f, mask, btab, wqf, wpf, cmb);
    hipLaunchKernelGGL(k1_xyfrag, dim3(12,2048), dim3(256), 0, stream, x, y, xyf);
    hipLaunchKernelGGL(k_fused,   dim3(2048),    dim3(256), 0, stream,
                       xyf, wqf, wpf, bqkv, bproj, cmb, out);
  } else {
    unsigned short* wq  = (unsigned short*)d_ws;
    unsigned short* wp  = (unsigned short*)((char*)d_ws + FB_WP_OFF);
    float*          cmb = (float*)((char*)d_ws + FB_COMB_OFF);
    hipLaunchKernelGGL(prep_weights_fb, dim3(2016), dim3(256), 0, stream, wq_f, wp_f, wq, wp);
    hipLaunchKernelGGL(prep_comb_fb,    dim3(6144), dim3(256), 0, stream, mask, btab, cmb);
    hipLaunchKernelGGL(fused_attn_fb,   dim3(2048), dim3(256), 0, stream,
                       x, y, bqkv, bproj, wq, wp, cmb, out);
  }
}

// Round 14
// 221.370 us; speedup vs baseline: 4.6681x; 4.6681x over previous
//
#include <hip/hip_runtime.h>
#include <hip/hip_bf16.h>

// WindowAttention, round 14 = exact revert to the round-11 champion (220.6 us).
// R13's barrier-halving regressed 4.7x: dropping the LDS A-panel forced 6x
// per-head xyf re-reads (FETCH 136MB -> 1.39GB, L2 thrash) and wave-local proj
// quadrupled wpf traffic. The R8/R11 fusion's core value is the A-panel staying
// LDS-resident across all 6 heads. Final structure:
//  k0_wfrag : w_qkv/w_proj f32 -> bf16 MFMA B-fragment layout (SCALE folded)
//  prep_comb: (rpb+mask) combined table, pad cols = -1e30
//  k_fused  : per window (2048 x 256thr, 80KiB LDS, 2 blk/CU):
//    stage concat(x,y)->A-frags in LDS once (dest-linear, conflict-free);
//    per head: QKV GEMM (A: linear ds_read_b128, B: 2-deep global dbuf,
//    bias in C-init) -> scatter q/k/vt -> barrier -> swapped QK^T ->
//    in-lane softmax -> pre-normalized P -> PV -> obuf -> barrier ->
//    K-split proj accumulating in registers; epilogue stores f32 rows<49.
//  Micro-opts: v_cvt_pk_bf16_f32 packing, s_setprio(1) around MFMA clusters.

typedef __attribute__((ext_vector_type(8))) short short8;
typedef __attribute__((ext_vector_type(4))) float f32x4;

#define SCALE 0.17677669529663687f  // (192/6)^-0.5

// ---------------- ws layout ----------------
#define WQF_OFF    0ul
#define WQF_BYTES  (864ul*1024)                  // 6h*12ct*12kt frags
#define WPF_OFF    (WQF_OFF + WQF_BYTES)
#define WPF_BYTES  (144ul*1024)                  // 12ct*12kt frags
#define COMB_OFF   (WPF_OFF + WPF_BYTES)
#define COMB_BYTES (64ul*6*4096*4)
#define WS_NEED    (COMB_OFF + COMB_BYTES)       // ~7.3 MB

__device__ __forceinline__ unsigned short f2bf(float f){
  unsigned u = __builtin_bit_cast(unsigned, f);
  u = u + 0x7fffu + ((u >> 16) & 1u);            // round-to-nearest-even
  return (unsigned short)(u >> 16);
}
__device__ __forceinline__ unsigned long long pack4(float4 v){
  return (unsigned long long)f2bf(v.x) | ((unsigned long long)f2bf(v.y) << 16)
       | ((unsigned long long)f2bf(v.z) << 32) | ((unsigned long long)f2bf(v.w) << 48);
}

// HW bf16 converts (RNE, same as f2bf).
__device__ __forceinline__ unsigned short cvt1(float x){
  unsigned r;
  asm("v_cvt_pk_bf16_f32 %0, %1, %1" : "=v"(r) : "v"(x));
  return (unsigned short)r;
}
__device__ __forceinline__ uint2 pk4(float a, float b, float c, float d){
  unsigned lo, hi;
  asm("v_cvt_pk_bf16_f32 %0, %1, %2" : "=v"(lo) : "v"(a), "v"(b));
  asm("v_cvt_pk_bf16_f32 %0, %1, %2" : "=v"(hi) : "v"(c), "v"(d));
  return make_uint2(lo, hi);
}

// ---------------- prep: weights -> fragments ----------------
__global__ void k0_wfrag(const float* __restrict__ wq_f, const float* __restrict__ wp_f,
                         unsigned short* __restrict__ wqf, unsigned short* __restrict__ wpf){
  int t = blockIdx.x*256 + threadIdx.x;          // exactly 1008*64
  int fragidx = t >> 6, l = t & 63;
  const float* src; unsigned short* dst;
  float sc = 1.0f;
  if (fragidx < 864){
    int h = fragidx/144, rem = fragidx - h*144;
    int ct = rem/12, kt = rem - ct*12;
    int row = (ct>>2)*384 + h*64 + (ct&3)*16 + (l&15);
    src = wq_f + (long)row*384 + kt*32 + (l>>4)*8;
    dst = wqf + (long)fragidx*512 + l*8;
    if (ct < 4) sc = SCALE;                      // fold softmax scale into q-weights
  } else {
    int fid = fragidx - 864;
    int ct = fid/12, kt = fid - ct*12;
    int row = ct*16 + (l&15);
    src = wp_f + (long)row*384 + kt*32 + (l>>4)*8;
    dst = wpf + (long)fid*512 + l*8;
  }
  short8 v;
  #pragma unroll
  for (int e = 0; e < 8; ++e) v[e] = (short)f2bf(src[e] * sc);
  *(short8*)dst = v;
}

// comb[w][h][i][j] = rpb[h][i][j] + mask[w][i][j]; pad cols j>=49 -> -1e30
__global__ void prep_comb(const float* __restrict__ mask, const float* __restrict__ btab,
                          float* __restrict__ comb){
  int idx = blockIdx.x * 256 + threadIdx.x;      // < 64*6*4096
  int j = idx & 63, i = (idx >> 6) & 63, rest = idx >> 12;
  int h = rest % 6, w = rest / 6;
  float v;
  if (i < 49 && j < 49){
    int di = i / 7 - j / 7 + 6;
    int dj = i % 7 - j % 7 + 6;
    v = btab[(di * 13 + dj) * 6 + h] + mask[(w * 49 + i) * 49 + j];
  } else {
    v = (j >= 49) ? -1e30f : 0.0f;
  }
  comb[idx] = v;
}

// ---------------- fused kernel ----------------
// LDS 80 KiB: A-frags @0 (48K, lives whole kernel), q@49152, k@57344,
// vt@65536 (XOR-swizzled [64][64] bf16), obuf @73728 (8K, O in frag layout).
__device__ __forceinline__ int swz(int r, int b){ return b ^ ((r & 7) << 4); }
__device__ __forceinline__ int a_q (int r, int c){ return 49152 + swz(r, r*128 + c*2); }
__device__ __forceinline__ int a_k (int r, int c){ return 57344 + swz(r, r*128 + c*2); }
__device__ __forceinline__ int a_vt(int r, int c){ return 65536 + swz(r, r*128 + c*2); }
#define OBUF 73728

__global__ __launch_bounds__(256, 2)
void k_fused(const float* __restrict__ x, const float* __restrict__ y,
             const unsigned short* __restrict__ wqf, const unsigned short* __restrict__ wpf,
             const float* __restrict__ bqkv, const float* __restrict__ bproj,
             const float* __restrict__ comb, float* __restrict__ out){
  __shared__ __align__(16) unsigned char smem[81920];
  const int win = blockIdx.x;
  const int tid = threadIdx.x, w = tid>>6, l = tid&63, l15 = l&15, lg = l>>4;

  // ---- stage concat(x,y) -> A-frags in LDS, dest-linear writes ----
  #pragma unroll
  for (int i = 0; i < 12; ++i){
    int f  = w*12 + i;                     // wave w stages frags w*12..w*12+11
    int kt = f >> 2, mt = f & 3;
    int row = mt*16 + l15;
    int c   = kt*32 + lg*8;                // wave-uniform branch below
    uint4 vv = make_uint4(0,0,0,0);
    if (row < 49){
      const float* src = (c < 192) ? (x + ((long)win*49 + row)*192 + c)
                                   : (y + ((long)win*49 + row)*192 + (c - 192));
      float4 f0 = *(const float4*)src, f1 = *(const float4*)(src + 4);
      uint2 lo = pk4(f0.x, f0.y, f0.z, f0.w);
      uint2 hi = pk4(f1.x, f1.y, f1.z, f1.w);
      vv = make_uint4(lo.x, lo.y, hi.x, hi.y);
    }
    *(uint4*)(smem + f*1024 + l*16) = vv;
  }

  // proj accumulators: bias in C-init, live across the head loop
  int np[3];
  f32x4 pacc[4][3];
  #pragma unroll
  for (int nt = 0; nt < 3; ++nt){
    np[nt] = w*48 + nt*16 + l15;
    float bv = bproj[np[nt]];
    #pragma unroll
    for (int mt = 0; mt < 4; ++mt)
      #pragma unroll
      for (int j = 0; j < 4; ++j) pacc[mt][nt][j] = bv;
  }

  __syncthreads();   // A-panel staged

  #pragma unroll 1
  for (int h = 0; h < 6; ++h){
    // comb tile prefetch (consumed post-QK^T; hides under the GEMM)
    const float* cb = comb + ((long)((win & 63)*6 + h))*4096 + (w*16 + l15)*64 + lg*4;
    float4 cbv[4];
    #pragma unroll
    for (int nt = 0; nt < 4; ++nt) cbv[nt] = *(const float4*)(cb + nt*16);

    float bias[3];
    #pragma unroll
    for (int nt = 0; nt < 3; ++nt){
      int ct = w*3 + nt, s = ct >> 2;
      bias[nt] = bqkv[s*384 + h*64 + (ct & 3)*16 + l15];
      if (s == 0) bias[nt] *= SCALE;
    }

    // ---- QKV GEMM: A from LDS, B dbuf from L2 (compiler-scheduled) ----
    const unsigned short* Bb = wqf + ((long)h*12 + w*3)*12*512;
    short8 bB[2][3];
    #pragma unroll
    for (int nt = 0; nt < 3; ++nt)
      bB[0][nt] = *(const short8*)(Bb + (nt*12)*512 + l*8);
    f32x4 acc[4][3];
    #pragma unroll
    for (int mt = 0; mt < 4; ++mt)
      #pragma unroll
      for (int nt = 0; nt < 3; ++nt)
        #pragma unroll
        for (int j = 0; j < 4; ++j) acc[mt][nt][j] = bias[nt];

    #pragma unroll
    for (int kt = 0; kt < 12; ++kt){
      const int cur = kt & 1, nxt = cur ^ 1;
      if (kt < 11){
        #pragma unroll
        for (int nt = 0; nt < 3; ++nt)
          bB[nxt][nt] = *(const short8*)(Bb + (nt*12 + kt+1)*512 + l*8);
      }
      short8 aA[4];
      #pragma unroll
      for (int mt = 0; mt < 4; ++mt)
        aA[mt] = *(const short8*)(smem + (kt*4 + mt)*1024 + l*16);
      __builtin_amdgcn_s_setprio(1);
      #pragma unroll
      for (int nt = 0; nt < 3; ++nt){
        #pragma unroll
        for (int mt = 0; mt < 4; ++mt)
          acc[mt][nt] = __builtin_amdgcn_mfma_f32_16x16x32_bf16(aA[mt], bB[cur][nt], acc[mt][nt], 0, 0, 0);
      }
      __builtin_amdgcn_s_setprio(0);
    }

    // ---- scatter q / k (b16) and vt (transposed, b64) to LDS ----
    #pragma unroll
    for (int nt = 0; nt < 3; ++nt){
      int ct = w*3 + nt, s = ct >> 2, d16 = (ct & 3) * 16;
      if (s == 2){
        #pragma unroll
        for (int mt = 0; mt < 4; ++mt){
          uint2 p = pk4(acc[mt][nt][0], acc[mt][nt][1], acc[mt][nt][2], acc[mt][nt][3]);
          *(uint2*)(smem + a_vt(d16 + l15, mt*16 + lg*4)) = p;
        }
      } else {
        #pragma unroll
        for (int mt = 0; mt < 4; ++mt){
          #pragma unroll
          for (int j = 0; j < 4; ++j){
            int row = mt*16 + lg*4 + j;
            int addr = (s == 0) ? a_q(row, d16 + l15) : a_k(row, d16 + l15);
            *(unsigned short*)(smem + addr) = cvt1(acc[mt][nt][j]);
          }
        }
      }
    }
    __syncthreads();   // (a) q/k/vt ready

    // ---- S^T = K * Q^T : lane owns q-row w*16+l15, holds 64 k-scores ----
    short8 bq[2];
    #pragma unroll
    for (int ks = 0; ks < 2; ++ks)
      bq[ks] = *(const short8*)(smem + a_q(w*16 + l15, ks*32 + lg*8));
    f32x4 st[4] = {};
    __builtin_amdgcn_s_setprio(1);
    #pragma unroll
    for (int ks = 0; ks < 2; ++ks){
      #pragma unroll
      for (int nt = 0; nt < 4; ++nt){
        short8 ak = *(const short8*)(smem + a_k(nt*16 + l15, ks*32 + lg*8));
        st[nt] = __builtin_amdgcn_mfma_f32_16x16x32_bf16(ak, bq[ks], st[nt], 0, 0, 0);
      }
    }
    __builtin_amdgcn_s_setprio(0);
    // + (rpb+mask); softmax over k: in-lane 16 + cross-lane ^16,^32
    #pragma unroll
    for (int nt = 0; nt < 4; ++nt){
      st[nt][0] += cbv[nt].x; st[nt][1] += cbv[nt].y;
      st[nt][2] += cbv[nt].z; st[nt][3] += cbv[nt].w;
    }
    float mx;
    {
      float m0 = fmaxf(fmaxf(st[0][0], st[0][1]), fmaxf(st[0][2], st[0][3]));
      float m1 = fmaxf(fmaxf(st[1][0], st[1][1]), fmaxf(st[1][2], st[1][3]));
      float m2 = fmaxf(fmaxf(st[2][0], st[2][1]), fmaxf(st[2][2], st[2][3]));
      float m3 = fmaxf(fmaxf(st[3][0], st[3][1]), fmaxf(st[3][2], st[3][3]));
      mx = fmaxf(fmaxf(m0, m1), fmaxf(m2, m3));
    }
    mx = fmaxf(mx, __shfl_xor(mx, 16));
    mx = fmaxf(mx, __shfl_xor(mx, 32));
    float ssum = 0.f;
    #pragma unroll
    for (int nt = 0; nt < 4; ++nt){
      #pragma unroll
      for (int j = 0; j < 4; ++j){
        float e = __expf(st[nt][j] - mx);
        st[nt][j] = e; ssum += e;
      }
    }
    ssum += __shfl_xor(ssum, 16);
    ssum += __shfl_xor(ssum, 32);
    const float inv = 1.0f / ssum;

    // pre-normalized P -> q buffer (own rows; b64 writes)
    #pragma unroll
    for (int nt = 0; nt < 4; ++nt){
      uint2 p = pk4(st[nt][0]*inv, st[nt][1]*inv, st[nt][2]*inv, st[nt][3]*inv);
      *(uint2*)(smem + a_q(w*16 + l15, nt*16 + lg*4)) = p;
    }

    // ---- O = Pn * V ----
    short8 ap[2];
    #pragma unroll
    for (int ks = 0; ks < 2; ++ks)
      ap[ks] = *(const short8*)(smem + a_q(w*16 + l15, ks*32 + lg*8));
    f32x4 oacc[4] = {};
    __builtin_amdgcn_s_setprio(1);
    #pragma unroll
    for (int ks = 0; ks < 2; ++ks){
      #pragma unroll
      for (int nt = 0; nt < 4; ++nt){
        short8 bv = *(const short8*)(smem + a_vt(nt*16 + l15, ks*32 + lg*8));
        oacc[nt] = __builtin_amdgcn_mfma_f32_16x16x32_bf16(ap[ks], bv, oacc[nt], 0, 0, 0);
      }
    }
    __builtin_amdgcn_s_setprio(0);
    // O[r=w*16+lg*4+j][c=nt*16+l15] -> obuf in A-frag layout (scalar bf16 writes)
    #pragma unroll
    for (int nt = 0; nt < 4; ++nt){
      int frag  = (nt >> 1)*4 + w;
      int chunk0 = (lg*4) + ((nt & 1)*2 + (l15 >> 3))*16;
      #pragma unroll
      for (int j = 0; j < 4; ++j){
        int addr = OBUF + frag*1024 + (chunk0 + j)*16 + (l15 & 7)*2;
        *(unsigned short*)(smem + addr) = cvt1(oacc[nt][j]);
      }
    }
    __syncthreads();   // (b) obuf ready

    // ---- proj partial GEMM: pacc += O_head @ wp[:, h*64:(h+1)*64]^T ----
    #pragma unroll
    for (int ks = 0; ks < 2; ++ks){
      short8 aO[4];
      #pragma unroll
      for (int mt = 0; mt < 4; ++mt)
        aO[mt] = *(const short8*)(smem + OBUF + (ks*4 + mt)*1024 + l*16);
      __builtin_amdgcn_s_setprio(1);
      #pragma unroll
      for (int nt = 0; nt < 3; ++nt){
        short8 bb = *(const short8*)(wpf + ((long)(w*3 + nt)*12 + h*2 + ks)*512 + l*8);
        #pragma unroll
        for (int mt = 0; mt < 4; ++mt)
          pacc[mt][nt] = __builtin_amdgcn_mfma_f32_16x16x32_bf16(aO[mt], bb, pacc[mt][nt], 0, 0, 0);
      }
      __builtin_amdgcn_s_setprio(0);
    }
  }

  // ---- epilogue: store f32 rows < 49 (bias already in pacc) ----
  #pragma unroll
  for (int mt = 0; mt < 4; ++mt){
    #pragma unroll
    for (int j = 0; j < 4; ++j){
      int row = mt*16 + lg*4 + j;
      if (row < 49){
        float* o = out + ((long)win*49 + row)*192;
        #pragma unroll
        for (int nt = 0; nt < 3; ++nt)
          o[np[nt]] = pacc[mt][nt][j];
      }
    }
  }
}

// ================= fallback (round-2 fused kernel, if ws too small) =================
#define FB_WQ_ELEMS (1152*384)
#define FB_WP_ELEMS (192*384)
#define FB_WP_OFF   (FB_WQ_ELEMS*2)
#define FB_COMB_OFF (FB_WP_OFF + FB_WP_ELEMS*2)

__global__ void prep_weights_fb(const float* __restrict__ wq_f, const float* __restrict__ wp_f,
                                unsigned short* __restrict__ wq, unsigned short* __restrict__ wp){
  int gid = blockIdx.x * 256 + threadIdx.x;
  if (gid < FB_WQ_ELEMS) wq[gid] = f2bf(wq_f[gid]);
  else { int g = gid - FB_WQ_ELEMS; if (g < FB_WP_ELEMS) wp[g] = f2bf(wp_f[g]); }
}
__global__ void prep_comb_fb(const float* __restrict__ mask, const float* __restrict__ btab,
                             float* __restrict__ comb){
  int idx = blockIdx.x * 256 + threadIdx.x;
  int j = idx & 63, i = (idx >> 6) & 63, rest = idx >> 12;
  int h = rest % 6, w = rest / 6;
  float v;
  if (i < 49 && j < 49){
    int di = i / 7 - j / 7 + 6;
    int dj = i % 7 - j % 7 + 6;
    v = btab[(di * 13 + dj) * 6 + h] + mask[(w * 49 + i) * 49 + j];
  } else {
    v = (j >= 49) ? -1e30f : 0.0f;
  }
  comb[idx] = v;
}
__device__ __forceinline__ int fb_xy(int r, int c){ return 0      + swz(r, r*768 + c*2); }
__device__ __forceinline__ int fb_q (int r, int c){ return 49152  + swz(r, r*128 + c*2); }
__device__ __forceinline__ int fb_k (int r, int c){ return 57344  + swz(r, r*128 + c*2); }
__device__ __forceinline__ int fb_vt(int r, int c){ return 65536  + swz(r, r*128 + c*2); }
__device__ __forceinline__ int fb_p (int r, int c){ return 73728  + swz(r, r*128 + c*2); }

__global__ __launch_bounds__(256, 2)
void fused_attn_fb(const float* __restrict__ x, const float* __restrict__ y,
                   const float* __restrict__ bqkv, const float* __restrict__ bproj,
                   const unsigned short* __restrict__ wq, const unsigned short* __restrict__ wp,
                   const float* __restrict__ comb, float* __restrict__ out){
  __shared__ __align__(16) unsigned char smem[81920];
  const int b = blockIdx.x, tid = threadIdx.x;
  const int w = tid>>6, l = tid&63, l15 = l&15, lg = l>>4;
  {
    const float4* x4 = (const float4*)x + b * 2352;
    const float4* y4 = (const float4*)y + b * 2352;
    for (int idx = tid; idx < 2352; idx += 256){
      int r = idx / 48, c4 = (idx % 48) * 4;
      float4 vx = x4[idx], vy = y4[idx];
      *(unsigned long long*)(smem + fb_xy(r, c4))       = pack4(vx);
      *(unsigned long long*)(smem + fb_xy(r, 192 + c4)) = pack4(vy);
    }
    for (int idx = tid; idx < 1440; idx += 256){
      int r = 49 + idx / 96, c4 = (idx % 96) * 4;
      *(unsigned long long*)(smem + fb_xy(r, c4)) = 0ull;
    }
  }
  __syncthreads();
  const float* cbB = comb + (long)(b & 63) * (6 * 4096);
  f32x4 pacc[4][3] = {};
  int np[3]; float bp[3];
  #pragma unroll
  for (int nt = 0; nt < 3; ++nt){ np[nt] = w*48 + nt*16 + l15; bp[nt] = bproj[np[nt]]; }
  #pragma unroll 1
  for (int h = 0; h < 6; ++h){
    f32x4 acc[4][3] = {};
    int wrow[3]; float bias[3];
    #pragma unroll
    for (int nt = 0; nt < 3; ++nt){
      int n = np[nt];
      wrow[nt] = (n >> 6) * 384 + h * 64 + (n & 63);
      bias[nt] = bqkv[wrow[nt]];
    }
    #pragma unroll 4
    for (int kt = 0; kt < 12; ++kt){
      int k0 = kt * 32;
      short8 a[4];
      #pragma unroll
      for (int mt = 0; mt < 4; ++mt)
        a[mt] = *(const short8*)(smem + fb_xy(mt*16 + l15, k0 + lg*8));
      #pragma unroll
      for (int nt = 0; nt < 3; ++nt){
        short8 bb = *(const short8*)(wq + (long)wrow[nt]*384 + k0 + lg*8);
        #pragma unroll
        for (int mt = 0; mt < 4; ++mt)
          acc[mt][nt] = __builtin_amdgcn_mfma_f32_16x16x32_bf16(a[mt], bb, acc[mt][nt], 0, 0, 0);
      }
    }
    #pragma unroll
    for (int nt = 0; nt < 3; ++nt){
      int n = np[nt], s = n >> 6, d = n & 63;
      #pragma unroll
      for (int mt = 0; mt < 4; ++mt){
        #pragma unroll
        for (int j = 0; j < 4; ++j){
          int row = mt*16 + lg*4 + j;
          float v = acc[mt][nt][j] + bias[nt];
          if (s == 0) v *= SCALE;
          int addr = (s==0) ? fb_q(row,d) : (s==1) ? fb_k(row,d) : fb_vt(d,row);
          *(unsigned short*)(smem + addr) = f2bf(v);
        }
      }
    }
    __syncthreads();
    short8 aq[2];
    #pragma unroll
    for (int ks = 0; ks < 2; ++ks)
      aq[ks] = *(const short8*)(smem + fb_q(w*16 + l15, ks*32 + lg*8));
    f32x4 sacc[4] = {};
    #pragma unroll
    for (int ks = 0; ks < 2; ++ks)
      #pragma unroll
      for (int nt = 0; nt < 4; ++nt){
        short8 bk = *(const short8*)(smem + fb_k(nt*16 + l15, ks*32 + lg*8));
        sacc[nt] = __builtin_amdgcn_mfma_f32_16x16x32_bf16(aq[ks], bk, sacc[nt], 0, 0, 0);
      }
    const float* cb = cbB + h * 4096;
    float rs[4];
    #pragma unroll
    for (int j = 0; j < 4; ++j){
      int r = w*16 + lg*4 + j;
      #pragma unroll
      for (int nt = 0; nt < 4; ++nt) sacc[nt][j] += cb[r*64 + nt*16 + l15];
      float m = fmaxf(fmaxf(sacc[0][j], sacc[1][j]), fmaxf(sacc[2][j], sacc[3][j]));
      #pragma unroll
      for (int dlt = 1; dlt < 16; dlt <<= 1) m = fmaxf(m, __shfl_xor(m, dlt));
      float ssum = 0.f;
      #pragma unroll
      for (int nt = 0; nt < 4; ++nt){
        float e = __expf(sacc[nt][j] - m);
        sacc[nt][j] = e; ssum += e;
      }
      #pragma unroll
      for (int dlt = 1; dlt < 16; dlt <<= 1) ssum += __shfl_xor(ssum, dlt);
      rs[j] = ssum;
      #pragma unroll
      for (int nt = 0; nt < 4; ++nt)
        *(unsigned short*)(smem + fb_p(r, nt*16 + l15)) = f2bf(sacc[nt][j]);
    }
    short8 ap[2];
    #pragma unroll
    for (int ks = 0; ks < 2; ++ks)
      ap[ks] = *(const short8*)(smem + fb_p(w*16 + l15, ks*32 + lg*8));
    f32x4 oacc[4] = {};
    #pragma unroll
    for (int ks = 0; ks < 2; ++ks)
      #pragma unroll
      for (int nt = 0; nt < 4; ++nt){
        short8 bv = *(const short8*)(smem + fb_vt(nt*16 + l15, ks*32 + lg*8));
        oacc[nt] = __builtin_amdgcn_mfma_f32_16x16x32_bf16(ap[ks], bv, oacc[nt], 0, 0, 0);
      }
    float inv[4];
    #pragma unroll
    for (int j = 0; j < 4; ++j) inv[j] = 1.0f / rs[j];
    #pragma unroll
    for (int nt = 0; nt < 4; ++nt)
      #pragma unroll
      for (int j = 0; j < 4; ++j){
        int row = w*16 + lg*4 + j;
        *(unsigned short*)(smem + fb_p(row, nt*16 + l15)) = f2bf(oacc[nt][j] * inv[j]);
      }
    __syncthreads();
    #pragma unroll
    for (int ks = 0; ks < 2; ++ks){
      short8 ao8[4];
      #pragma unroll
      for (int mt = 0; mt < 4; ++mt)
        ao8[mt] = *(const short8*)(smem + fb_p(mt*16 + l15, ks*32 + lg*8));
      #pragma unroll
      for (int nt = 0; nt < 3; ++nt){
        short8 bb = *(const short8*)(wp + (long)np[nt]*384 + h*64 + ks*32 + lg*8);
        #pragma unroll
        for (int mt = 0; mt < 4; ++mt)
          pacc[mt][nt] = __builtin_amdgcn_mfma_f32_16x16x32_bf16(ao8[mt], bb, pacc[mt][nt], 0, 0, 0);
      }
    }
  }
  #pragma unroll
  for (int mt = 0; mt < 4; ++mt)
    #pragma unroll
    for (int j = 0; j < 4; ++j){
      int row = mt*16 + lg*4 + j;
      if (row < 49){
        float* o = out + ((long)b*49 + row)*192;
        #pragma unroll
        for (int nt = 0; nt < 3; ++nt)
          o[np[nt]] = pacc[mt][nt][j] + bp[nt];
      }
    }
}

// ---------------- launch ----------------
extern "C" void kernel_launch(void* const* d_in, const int* in_sizes, int n_in,
                              void* d_out, int out_size, void* d_ws, size_t ws_size,
                              hipStream_t stream){
  (void)in_sizes; (void)n_in; (void)out_size;
  const float* x     = (const float*)d_in[0];
  const float* y     = (const float*)d_in[1];
  const float* mask  = (const float*)d_in[2];
  const float* wq_f  = (const float*)d_in[3];
  const float* bqkv  = (const float*)d_in[4];
  const float* wp_f  = (const float*)d_in[5];
  const float* bproj = (const float*)d_in[6];
  const float* btab  = (const float*)d_in[7];
  float* out = (float*)d_out;

  if (ws_size >= WS_NEED){
    unsigned short* wqf = (unsigned short*)((char*)d_ws + WQF_OFF);
    unsigned short* wpf = (unsigned short*)((char*)d_ws + WPF_OFF);
    float*          cmb = (float*)((char*)d_ws + COMB_OFF);
    hipLaunchKernelGGL(k0_wfrag,  dim3(252),  dim3(256), 0, stream, wq_f, wp_f, wqf, wpf);
    hipLaunchKernelGGL(prep_comb, dim3(6144), dim3(256), 0, stream, mask, btab, cmb);
    hipLaunchKernelGGL(k_fused,   dim3(2048), dim3(256), 0, stream,
                       x, y, wqf, wpf, bqkv, bproj, cmb, out);
  } else {
    unsigned short* wq  = (unsigned short*)d_ws;
    unsigned short* wp  = (unsigned short*)((char*)d_ws + FB_WP_OFF);
    float*          cmb = (float*)((char*)d_ws + FB_COMB_OFF);
    hipLaunchKernelGGL(prep_weights_fb, dim3(2016), dim3(256), 0, stream, wq_f, wp_f, wq, wp);
    hipLaunchKernelGGL(prep_comb_fb,    dim3(6144), dim3(256), 0, stream, mask, btab, cmb);
    hipLaunchKernelGGL(fused_attn_fb,   dim3(2048), dim3(256), 0, stream,
                       x, y, bqkv, bproj, wq, wp, cmb, out);
  }
}